// Round 14
// baseline (288.167 us; speedup 1.0000x reference)
//
#include <hip/hip_runtime.h>
#include <hip/hip_bf16.h>
#include <math.h>

// Problem constants
#define B_   512
#define KEV  64
#define NN   1024
#define DD   128
#define EE_  1024
#define HH   256
#define PP   12

typedef __bf16 bf16x8 __attribute__((ext_vector_type(8)));
typedef float  f32x4  __attribute__((ext_vector_type(4)));

static __device__ __forceinline__ unsigned short f2bf(float f) {
    unsigned int u = __builtin_bit_cast(unsigned int, f);
    u = (u + 0x7FFFu + ((u >> 16) & 1u)) >> 16;   // RNE
    return (unsigned short)u;
}

// HW packed f32->bf16 (RNE): 4 instructions per 8 elements
static __device__ __forceinline__ bf16x8 cvt8(f32x4 lo, f32x4 hi) {
    unsigned int r0, r1, r2, r3;
    asm("v_cvt_pk_bf16_f32 %0, %1, %2" : "=v"(r0) : "v"(lo[0]), "v"(lo[1]));
    asm("v_cvt_pk_bf16_f32 %0, %1, %2" : "=v"(r1) : "v"(lo[2]), "v"(lo[3]));
    asm("v_cvt_pk_bf16_f32 %0, %1, %2" : "=v"(r2) : "v"(hi[0]), "v"(hi[1]));
    asm("v_cvt_pk_bf16_f32 %0, %1, %2" : "=v"(r3) : "v"(hi[2]), "v"(hi[3]));
    union { unsigned int u[4]; bf16x8 v; } o;
    o.u[0] = r0; o.u[1] = r1; o.u[2] = r2; o.u[3] = r3;
    return o.v;
}

// ---------------------------------------------------------------------------
// prep (blocks 0..255): W_t f32 -> bf16.  block 256: detect dtypes + build Wc.
//   flags[0] = event_idx is int64 (1) or int32 (0)
//   flags[1] = event_mask repr: 0=uint8, 1=int32, 2=int64
// ---------------------------------------------------------------------------
__global__ __launch_bounds__(256) void prep_kernel(
    const float* __restrict__ Wt,
    const float* __restrict__ Wmm,
    const float* __restrict__ Wts,
    const unsigned int* __restrict__ idxW,
    const unsigned int* __restrict__ mskW,
    unsigned short* __restrict__ WtBf,
    float* __restrict__ Wc,
    int* __restrict__ flags)
{
    if (blockIdx.x < 256) {
        int i4 = (blockIdx.x * 256 + threadIdx.x) * 4;
        const float4 v = *reinterpret_cast<const float4*>(Wt + i4);
        ushort4 o = make_ushort4(f2bf(v.x), f2bf(v.y), f2bf(v.z), f2bf(v.w));
        *reinterpret_cast<ushort4*>(WtBf + i4) = o;
        return;
    }
    __shared__ int any_nz;
    if (threadIdx.x == 0) any_nz = 0;
    __syncthreads();
    int local = 0;
    for (int k = threadIdx.x; k < (B_ * KEV) / 2; k += 256)
        local |= (idxW[2 * k + 1] != 0u);
    if (local) atomicOr(&any_nz, 1);
    for (int k = threadIdx.x; k < PP * DD; k += 256) {
        int p = k >> 7, d = k & 127;
        Wc[k] = Wmm[p * (HH + DD) + HH + d] + Wts[p * DD + d];
    }
    __syncthreads();
    if (threadIdx.x == 0) {
        flags[0] = any_nz ? 0 : 1;                 // 1 => idx is int64
        unsigned int w0 = mskW[0], w1 = mskW[1];
        flags[1] = (w0 == 0x01010101u) ? 0 : ((w1 == 0u) ? 2 : 1);
    }
}

// ---------------------------------------------------------------------------
// fused, BARRIER-FREE main loop, m-split:
//   wave w: events [16w,16w+16) x all 256 h (A direct-load, zero redundancy,
//           in-register cvt_pk; B from L2-hot WtBf)  +  ts columns
//           [256w,+256) with private d-reduction, 4 d-rows per ks iteration.
// No LDS staging, no __syncthreads, no vmcnt(0) drains until the epilogue —
// gather + stream traffic mix freely in each wave's scheduled stream.
// Epilogue: per-wave masked max -> LDS partials -> combine -> projection ->
// all waves store 0.5*(tacc + c).
// ---------------------------------------------------------------------------
__global__ __launch_bounds__(256, 2) void fused_kernel(
    const float* __restrict__ table,
    const void* __restrict__ idxRaw,
    const void* __restrict__ maskRaw,
    const int* __restrict__ flags,
    const unsigned short* __restrict__ WtBf,
    const float* __restrict__ bt,
    const float* __restrict__ Wmm,
    const float* __restrict__ bmm,
    const float* __restrict__ bts,
    const float* __restrict__ Wc,
    const float* __restrict__ ts,
    float* __restrict__ out)
{
    const int b = blockIdx.x;
    const int t = threadIdx.x;
    const int w = t >> 6;        // wave id
    const int l = t & 63;        // lane
    const int lm = l & 15;
    const int lg = l >> 4;

    __shared__ int           sIdx[KEV];
    __shared__ unsigned char sMask[KEV];
    __shared__ float         sWcT[DD * PP];   // transposed: [d][p], 6KB
    __shared__ float         sEvP[4 * HH];    // per-wave partial max
    __shared__ float         sEv[HH];
    __shared__ float         sC[PP];

    if (t < KEV) {
        const int i = b * KEV + t;
        int id;
        if (flags[0]) id = (int)((const long long*)idxRaw)[i];
        else          id = ((const int*)idxRaw)[i];
        sIdx[t] = id;
        const int mm = flags[1];
        bool mk;
        if      (mm == 0) mk = ((const unsigned char*)maskRaw)[i] != 0;
        else if (mm == 1) mk = ((const int*)maskRaw)[i] != 0;
        else              mk = ((const long long*)maskRaw)[i] != 0;
        sMask[t] = mk ? 1 : 0;
    }
    for (int k = t; k < DD * PP; k += 256) {
        const int d = k / PP, p = k - d * PP;
        sWcT[k] = Wc[p * DD + d];
    }
    __syncthreads();   // staging barrier (before main loop only)

    // ---- per-lane pointers ----
    // A: event row 16w+lm, elements ks*32 + lg*8 (32B contiguous per lane)
    const float* aptr = table + (size_t)sIdx[w * 16 + lm] * EE_ + lg * 8;
    // B: h row ni*16+lm, same k-slice
    const unsigned short* wtB = WtBf + (size_t)lm * EE_ + lg * 8;
    // ts: column block [256w, +256), this lane's 4 columns
    const float* tsb = ts + (size_t)b * DD * NN + w * 256 + (l << 2);

    f32x4 acc[16];
    #pragma unroll
    for (int ni = 0; ni < 16; ++ni) acc[ni] = (f32x4){0.f, 0.f, 0.f, 0.f};
    f32x4 tacc[PP];
    #pragma unroll
    for (int p = 0; p < PP; ++p) tacc[p] = (f32x4){0.f, 0.f, 0.f, 0.f};

    #pragma unroll 1
    for (int ks = 0; ks < 32; ++ks) {
        // event A-frag: direct load + in-register convert
        const f32x4 alo = *reinterpret_cast<const f32x4*>(aptr + ks * 32);
        const f32x4 ahi = *reinterpret_cast<const f32x4*>(aptr + ks * 32 + 4);
        // ts chunk: 4 d-rows
        f32x4 tv0 = *reinterpret_cast<const f32x4*>(tsb + (size_t)(ks * 4 + 0) * NN);
        f32x4 tv1 = *reinterpret_cast<const f32x4*>(tsb + (size_t)(ks * 4 + 1) * NN);
        f32x4 tv2 = *reinterpret_cast<const f32x4*>(tsb + (size_t)(ks * 4 + 2) * NN);
        f32x4 tv3 = *reinterpret_cast<const f32x4*>(tsb + (size_t)(ks * 4 + 3) * NN);

        const bf16x8 af = cvt8(alo, ahi);
        #pragma unroll
        for (int ni = 0; ni < 16; ++ni) {
            const bf16x8 bfr = *reinterpret_cast<const bf16x8*>(
                wtB + (size_t)ni * 16 * EE_ + ks * 32);
            acc[ni] = __builtin_amdgcn_mfma_f32_16x16x32_bf16(af, bfr, acc[ni], 0, 0, 0);
        }

        // ts FMAs (Wc broadcast from LDS, transposed rows of 12)
        #pragma unroll
        for (int j = 0; j < 4; ++j) {
            const int d = ks * 4 + j;
            const f32x4 wv0 = *reinterpret_cast<const f32x4*>(&sWcT[d * PP]);
            const f32x4 wv1 = *reinterpret_cast<const f32x4*>(&sWcT[d * PP + 4]);
            const f32x4 wv2 = *reinterpret_cast<const f32x4*>(&sWcT[d * PP + 8]);
            const f32x4 tv = (j == 0) ? tv0 : (j == 1) ? tv1 : (j == 2) ? tv2 : tv3;
            tacc[0]  += wv0[0] * tv;  tacc[1]  += wv0[1] * tv;
            tacc[2]  += wv0[2] * tv;  tacc[3]  += wv0[3] * tv;
            tacc[4]  += wv1[0] * tv;  tacc[5]  += wv1[1] * tv;
            tacc[6]  += wv1[2] * tv;  tacc[7]  += wv1[3] * tv;
            tacc[8]  += wv2[0] * tv;  tacc[9]  += wv2[1] * tv;
            tacc[10] += wv2[2] * tv;  tacc[11] += wv2[3] * tv;
        }
    }

    // ---- epilogue ----
    // per-wave masked max over its 16 events.
    // C/D layout: h = ni*16 + lm (col); event-within-wave = lg*4 + r (row)
    #pragma unroll
    for (int ni = 0; ni < 16; ++ni) {
        float mx = -INFINITY;
        #pragma unroll
        for (int r = 0; r < 4; ++r) {
            const int ev = w * 16 + lg * 4 + r;
            const float v = sMask[ev] ? acc[ni][r] : -INFINITY;
            mx = fmaxf(mx, v);
        }
        mx = fmaxf(mx, __shfl_xor(mx, 16));
        mx = fmaxf(mx, __shfl_xor(mx, 32));
        if (lg == 0) sEvP[w * HH + ni * 16 + lm] = mx;
    }
    __syncthreads();

    // combine 4 wave-partials + bias: thread t handles h = t
    {
        const float m01 = fmaxf(sEvP[t], sEvP[HH + t]);
        const float m23 = fmaxf(sEvP[2 * HH + t], sEvP[3 * HH + t]);
        sEv[t] = fmaxf(m01, m23) + bt[t];
    }
    __syncthreads();

    // c[p] = sum_h ev_emb[h] * W_mm[p][h] + b_mm[p] + b_ts[p]   (wave 0)
    if (w == 0) {
        #pragma unroll 1
        for (int p = 0; p < PP; ++p) {
            const float* wr = Wmm + p * (HH + DD);
            float sum = sEv[l]       * wr[l]
                      + sEv[l + 64]  * wr[l + 64]
                      + sEv[l + 128] * wr[l + 128]
                      + sEv[l + 192] * wr[l + 192];
            #pragma unroll
            for (int off = 32; off >= 1; off >>= 1) sum += __shfl_xor(sum, off);
            if (l == 0) sC[p] = sum + bmm[p] + bts[p];
        }
    }
    __syncthreads();

    // store: out = 0.5 * (tacc + c)
    float* ob = out + (size_t)b * PP * NN + w * 256 + (l << 2);
    #pragma unroll
    for (int p = 0; p < PP; ++p) {
        const float c = sC[p];
        const f32x4 r = (tacc[p] + (f32x4){c, c, c, c}) * 0.5f;
        __builtin_nontemporal_store(r, reinterpret_cast<f32x4*>(ob + (size_t)p * NN));
    }
}

// ---------------------------------------------------------------------------
extern "C" void kernel_launch(void* const* d_in, const int* in_sizes, int n_in,
                              void* d_out, int out_size, void* d_ws, size_t ws_size,
                              hipStream_t stream)
{
    const float* ts    = (const float*)d_in[0];
    const float* table = (const float*)d_in[1];
    const float* Wt    = (const float*)d_in[2];
    const float* bt    = (const float*)d_in[3];
    const float* Wmm   = (const float*)d_in[4];
    const float* bmm   = (const float*)d_in[5];
    const float* Wts   = (const float*)d_in[6];
    const float* bts   = (const float*)d_in[7];
    const void*  idx   = (const void*)d_in[8];
    const void*  msk   = (const void*)d_in[9];
    float* out = (float*)d_out;

    // ws layout: [0, 512KB) W_t bf16; [512KB, +8KB) Wc; flags
    unsigned short* WtBf = (unsigned short*)d_ws;
    float* Wc  = (float*)((char*)d_ws + (512u << 10));
    int*   flg = (int*)((char*)d_ws + (512u << 10) + 8192);

    prep_kernel<<<257, 256, 0, stream>>>(Wt, Wmm, Wts,
                                         (const unsigned int*)idx,
                                         (const unsigned int*)msk,
                                         WtBf, Wc, flg);
    fused_kernel<<<B_, 256, 0, stream>>>(table, idx, msk, flg, WtBf, bt,
                                         Wmm, bmm, bts, Wc, ts, out);
}